// Round 1
// baseline (24080.191 us; speedup 1.0000x reference)
//
#include <hip/hip_runtime.h>
#include <hip/hip_bf16.h>
#include <math.h>

#define BATCH 64
#define HDIM  4096
#define VOCAB 128000
#define RMS_EPS 1e-5f

// ---------------- Kernel 1: RMSNorm ----------------
__global__ __launch_bounds__(256) void rmsnorm_kernel(
    const float* __restrict__ x, const float* __restrict__ w, float* __restrict__ h)
{
    int row = blockIdx.x;
    int t = threadIdx.x;
    const float4* x4 = (const float4*)(x + (size_t)row * HDIM);
    float4 v[4];
    float ss = 0.f;
#pragma unroll
    for (int i = 0; i < 4; i++) {
        v[i] = x4[t + 256 * i];
        ss += v[i].x * v[i].x + v[i].y * v[i].y + v[i].z * v[i].z + v[i].w * v[i].w;
    }
    __shared__ float red[256];
    red[t] = ss;
    __syncthreads();
    for (int off = 128; off > 0; off >>= 1) {
        if (t < off) red[t] += red[t + off];
        __syncthreads();
    }
    float rs = rsqrtf(red[0] / (float)HDIM + RMS_EPS);
    const float4* w4 = (const float4*)w;
    float4* h4 = (float4*)(h + (size_t)row * HDIM);
#pragma unroll
    for (int i = 0; i < 4; i++) {
        float4 wv = w4[t + 256 * i];
        float4 o;
        o.x = v[i].x * rs * wv.x;
        o.y = v[i].y * rs * wv.y;
        o.z = v[i].z * rs * wv.z;
        o.w = v[i].w * rs * wv.w;
        h4[t + 256 * i] = o;
    }
}

// ---------------- Kernel 2: fp32 GEMM logits = h @ W^T ----------------
// Tile: all 64 batch rows x 128 vocab rows per block; K-chunk 64.
// LDS stride 68 (pad +4): keeps float4 alignment; v-strided b128 reads get a
// contiguous-equivalent bank pattern.
#define VT 128
#define KT 64
#define LSTR 68

__global__ __launch_bounds__(256, 3) void gemm_kernel(
    const float* __restrict__ h, const float* __restrict__ W, float* __restrict__ logits)
{
    __shared__ float As[BATCH * LSTR];   // 64*68*4  = 17408 B
    __shared__ float Ws[VT * LSTR];      // 128*68*4 = 34816 B
    int t = threadIdx.x;
    int v0 = blockIdx.x * VT;
    int tv = t & 31;
    int tb = t >> 5;

    float acc[8][4];
#pragma unroll
    for (int i = 0; i < 8; i++)
#pragma unroll
        for (int j = 0; j < 4; j++) acc[i][j] = 0.f;

    for (int kc = 0; kc < HDIM / KT; kc++) {
        int k0 = kc * KT;
        // stage A: 64 rows x 16 float4
#pragma unroll
        for (int i = 0; i < 4; i++) {
            int e = t + 256 * i;
            int r = e >> 4, kq = e & 15;
            float4 f = *(const float4*)&h[(size_t)r * HDIM + k0 + kq * 4];
            *(float4*)&As[r * LSTR + kq * 4] = f;
        }
        // stage W: 128 rows x 16 float4
#pragma unroll
        for (int i = 0; i < 8; i++) {
            int e = t + 256 * i;
            int r = e >> 4, kq = e & 15;
            float4 f = *(const float4*)&W[(size_t)(v0 + r) * HDIM + k0 + kq * 4];
            *(float4*)&Ws[r * LSTR + kq * 4] = f;
        }
        __syncthreads();
#pragma unroll
        for (int kk = 0; kk < KT; kk += 4) {
            float4 a[8], wv[4];
#pragma unroll
            for (int i = 0; i < 8; i++) a[i] = *(const float4*)&As[(tb * 8 + i) * LSTR + kk];
#pragma unroll
            for (int j = 0; j < 4; j++) wv[j] = *(const float4*)&Ws[(tv + 32 * j) * LSTR + kk];
#pragma unroll
            for (int i = 0; i < 8; i++)
#pragma unroll
                for (int j = 0; j < 4; j++)
                    acc[i][j] += a[i].x * wv[j].x + a[i].y * wv[j].y +
                                 a[i].z * wv[j].z + a[i].w * wv[j].w;
        }
        __syncthreads();
    }
#pragma unroll
    for (int i = 0; i < 8; i++) {
        size_t rowoff = (size_t)(tb * 8 + i) * VOCAB + v0;
#pragma unroll
        for (int j = 0; j < 4; j++)
            logits[rowoff + tv + 32 * j] = acc[i][j];
    }
}

// ---------------- Kernel 3: softmax + sampling + topk ----------------
// One block (1024 threads) per batch row.
#define NT 1024
#define SEG 125   // 128000 / 1024

__global__ __launch_bounds__(NT, 1) void sample_kernel(
    const float* __restrict__ logits,
    const float* __restrict__ temperature,
    const float* __restrict__ uniform,
    const int* __restrict__ greedy_mask,
    float* __restrict__ out)
{
    int row = blockIdx.x;
    int t = threadIdx.x;
    const float* lrow = logits + (size_t)row * VOCAB;

    __shared__ float cval[NT * 8];   // 32 KB (also reused as scan buffer B)
    __shared__ int   cidx[NT * 8];   // 32 KB
    __shared__ float red_f[NT];      // 4 KB (also scan buffer A)
    __shared__ int   red_i[NT];
    __shared__ float top_vals[8];
    __shared__ int   top_idx[8];
    __shared__ int   sh_sampled;

    if (t == 0) sh_sampled = 0x7FFFFFFF;

    // ---- pass 1: per-thread top-8 over strided float4 stream ----
    float lv[8]; int li[8];
#pragma unroll
    for (int s = 0; s < 8; s++) { lv[s] = -INFINITY; li[s] = 0x7FFFFFFF; }
    const float4* lg4 = (const float4*)lrow;
    for (int vi = t; vi < VOCAB / 4; vi += NT) {
        float4 f = lg4[vi];
        int i0 = vi * 4;
        float vals[4] = { f.x, f.y, f.z, f.w };
#pragma unroll
        for (int c = 0; c < 4; c++) {
            float val = vals[c];
            if (val > lv[7]) {
                int p = 7;
                while (p > 0 && lv[p - 1] < val) {
                    lv[p] = lv[p - 1]; li[p] = li[p - 1]; p--;
                }
                lv[p] = val; li[p] = i0 + c;
            }
        }
    }
#pragma unroll
    for (int s = 0; s < 8; s++) { cval[t * 8 + s] = lv[s]; cidx[t * 8 + s] = li[s]; }
    __syncthreads();

    // ---- block top-8 selection, 8 rounds ----
    for (int r = 0; r < 8; r++) {
        float best = -INFINITY; int bidx = 0x7FFFFFFF; int bslot = -1;
#pragma unroll
        for (int s = 0; s < 8; s++) {
            float c = cval[t * 8 + s];
            int ci = cidx[t * 8 + s];
            if (c > best || (c == best && ci < bidx)) { best = c; bidx = ci; bslot = s; }
        }
        red_f[t] = best; red_i[t] = bidx;
        __syncthreads();
        for (int off = NT / 2; off > 0; off >>= 1) {
            if (t < off) {
                float o = red_f[t + off]; int oi = red_i[t + off];
                if (o > red_f[t] || (o == red_f[t] && oi < red_i[t])) {
                    red_f[t] = o; red_i[t] = oi;
                }
            }
            __syncthreads();
        }
        if (t == 0) { top_vals[r] = red_f[0]; top_idx[r] = red_i[0]; }
        __syncthreads();
        if (bslot >= 0 && best == top_vals[r] && bidx == top_idx[r]) {
            cval[t * 8 + bslot] = -INFINITY; cidx[t * 8 + bslot] = 0x7FFFFFFF;
        }
        __syncthreads();
    }

    float M = top_vals[0];           // row max
    int greedy_id = top_idx[0];      // first-occurrence argmax
    float invT = 1.0f / temperature[row];

    // ---- pass 2: segment exp-sums ----
    int segBase = t * SEG;
    float S = 0.f;
    for (int i = 0; i < SEG; i++)
        S += expf((lrow[segBase + i] - M) * invT);

    // Hillis-Steele inclusive scan over 1024 segment sums
    float* scanA = red_f;
    float* scanB = cval;  // reuse
    scanA[t] = S;
    __syncthreads();
    float* src = scanA; float* dst = scanB;
    for (int off = 1; off < NT; off <<= 1) {
        float v = src[t];
        if (t >= off) v += src[t - off];
        dst[t] = v;
        __syncthreads();
        float* tmp = src; src = dst; dst = tmp;
    }
    float incl = src[t];
    float excl = (t == 0) ? 0.f : src[t - 1];
    float total = src[NT - 1];
    float target = uniform[row] * total;

    if (excl < target && incl >= target) {
        float run = excl;
        int id = segBase + SEG - 1;  // fallback: last element of segment
        for (int i = 0; i < SEG; i++) {
            run += expf((lrow[segBase + i] - M) * invT);
            if (run >= target) { id = segBase + i; break; }
        }
        atomicMin(&sh_sampled, id);
    }
    __syncthreads();

    if (t == 0) {
        int sampled = (sh_sampled == 0x7FFFFFFF) ? 0 : sh_sampled;  // all-False -> 0
        int next = (greedy_mask[row] != 0) ? greedy_id : sampled;
        float logZ = logf(total);
        float lnext = lrow[next];
        float chosen_lp = (lnext - M) * invT - logZ;
        out[row] = (float)next;
        out[BATCH + row] = chosen_lp;
        for (int s = 0; s < 8; s++) {
            out[2 * BATCH + row * 8 + s] = (float)top_idx[s];
            out[2 * BATCH + BATCH * 8 + row * 8 + s] = (top_vals[s] - M) * invT - logZ;
        }
    }
}

// ---------------- launch ----------------
extern "C" void kernel_launch(void* const* d_in, const int* in_sizes, int n_in,
                              void* d_out, int out_size, void* d_ws, size_t ws_size,
                              hipStream_t stream) {
    const float* hidden   = (const float*)d_in[0];
    const float* temp     = (const float*)d_in[1];
    const float* uniform  = (const float*)d_in[2];
    const int*   gmask    = (const int*)d_in[3];
    const float* norm_w   = (const float*)d_in[4];
    const float* lm_w     = (const float*)d_in[5];
    float* out = (float*)d_out;

    float* ws_h      = (float*)d_ws;                         // 64*4096 floats = 1 MB
    float* ws_logits = ws_h + (size_t)BATCH * HDIM;          // 64*128000 floats = 32.8 MB

    rmsnorm_kernel<<<BATCH, 256, 0, stream>>>(hidden, norm_w, ws_h);
    gemm_kernel<<<VOCAB / VT, 256, 0, stream>>>(ws_h, lm_w, ws_logits);
    sample_kernel<<<BATCH, NT, 0, stream>>>(ws_logits, temp, uniform, gmask, out);
}